// Round 1
// 625.217 us; speedup vs baseline: 1.0488x; 1.0488x over previous
//
#include <hip/hip_runtime.h>
#include <math.h>

#define N0c 500000
#define Rc  100000
#define NDc 50000
#define E0c 2000000
#define E1c 1000000
#define GB0 128                 // graphs per set0 bucket
#define NB0 782                 // ceil(Rc/128)
#define DB1 128                 // dst nodes per set1 bucket
#define NB1 391                 // ceil(NDc/128)
#define NBk (NB0 + NB1)         // 1173
#define T0  8192                // set0 edges per partition tile
#define T1  4096                // set1 edges per partition tile
#define TN  2048                // nodes per partition tile
#define PB  245                 // ceil(E0c/T0); covers E1c/T1 and N0c/TN too
#define CAP 3584                // max edges per bucket (mean ~2560, sd ~51)
#define MTILE 32

// ---------------- coarse histogram (LDS-aggregated) + node counts ----------------
// 1024 threads: PB=245 blocks -> ~1 block/CU, 16 waves/CU (was 4) to hide gather latency
__global__ __launch_bounds__(1024) void k_hist_coarse(
        const int* __restrict__ dst0, const int* __restrict__ node_graph,
        const int* __restrict__ dst1, unsigned* __restrict__ cnt,
        unsigned* __restrict__ cntN) {
    __shared__ unsigned h[NBk];
    int tid = threadIdx.x, b = blockIdx.x;
    for (int i = tid; i < NBk; i += 1024) h[i] = 0u;
    __syncthreads();
    int base0 = b * T0, base1 = b * T1, baseN = b * TN;
    for (int i = tid; i < T0; i += 1024) {
        int e = base0 + i;
        if (e < E0c) atomicAdd(&h[node_graph[dst0[e]] >> 7], 1u);
    }
    for (int i = tid; i < T1; i += 1024) {
        int e = base1 + i;
        if (e < E1c) atomicAdd(&h[NB0 + (dst1[e] >> 7)], 1u);
    }
    for (int i = tid; i < TN; i += 1024) {
        int n = baseN + i;
        if (n < N0c) atomicAdd(&cntN[node_graph[n]], 1u);
    }
    __syncthreads();
    for (int i = tid; i < NBk; i += 1024) {
        unsigned v = h[i];
        if (v) atomicAdd(&cnt[i], v);
    }
}

// ---------------- 3-pass exclusive scan ----------------
__global__ void k_scan1(const unsigned* __restrict__ in, unsigned* __restrict__ out,
                        unsigned* __restrict__ bsum, int n) {
    __shared__ unsigned s[1024];
    int i = blockIdx.x * 1024 + threadIdx.x;
    unsigned v = (i < n) ? in[i] : 0u;
    s[threadIdx.x] = v;
    __syncthreads();
    for (int off = 1; off < 1024; off <<= 1) {
        unsigned t = (threadIdx.x >= off) ? s[threadIdx.x - off] : 0u;
        __syncthreads();
        s[threadIdx.x] += t;
        __syncthreads();
    }
    if (i < n) out[i] = s[threadIdx.x] - v;
    if (threadIdx.x == 1023) bsum[blockIdx.x] = s[1023];
}

__global__ void k_scan2(unsigned* __restrict__ bsum, int nb) {
    __shared__ unsigned s[1024];
    unsigned v = (threadIdx.x < nb) ? bsum[threadIdx.x] : 0u;
    s[threadIdx.x] = v;
    __syncthreads();
    for (int off = 1; off < 1024; off <<= 1) {
        unsigned t = (threadIdx.x >= off) ? s[threadIdx.x - off] : 0u;
        __syncthreads();
        s[threadIdx.x] += t;
        __syncthreads();
    }
    if (threadIdx.x < nb) bsum[threadIdx.x] = s[threadIdx.x] - v;
}

__global__ void k_scan3(unsigned* __restrict__ out, const unsigned* __restrict__ bsum,
                        unsigned* __restrict__ cursor, int n) {
    int i = blockIdx.x * 1024 + threadIdx.x;
    if (i < n) {
        unsigned v = out[i] + bsum[blockIdx.x];
        out[i] = v;
        cursor[i] = v;
    }
}

// ---------------- tiled coarse place: LDS hist -> range reserve -> run-scatter ----------------
// payload0: int2 { src | (g&127)<<19 , coef }   payload1: int { src | (d&127)<<17 }
// 1024 threads; runs per (tile,bucket) now ~10.5 edges (84B) -> fewer partial-line writes/RFO
__global__ __launch_bounds__(1024) void k_place_coarse(
        const int* __restrict__ src0, const int* __restrict__ dst0,
        const int* __restrict__ node_graph, const float* __restrict__ norm_n,
        const float* __restrict__ norm_e, const int* __restrict__ src1,
        const int* __restrict__ dst1, unsigned* __restrict__ gcur,
        int2* __restrict__ coarse0, int* __restrict__ coarse1) {
    __shared__ unsigned hc[NBk];
    __shared__ unsigned hb[NBk];
    int tid = threadIdx.x, b = blockIdx.x;
    for (int i = tid; i < NBk; i += 1024) hc[i] = 0u;
    __syncthreads();
    int base0 = b * T0, base1 = b * T1;
    for (int i = tid; i < T0; i += 1024) {
        int e = base0 + i;
        if (e < E0c) atomicAdd(&hc[node_graph[dst0[e]] >> 7], 1u);
    }
    for (int i = tid; i < T1; i += 1024) {
        int e = base1 + i;
        if (e < E1c) atomicAdd(&hc[NB0 + (dst1[e] >> 7)], 1u);
    }
    __syncthreads();
    for (int i = tid; i < NBk; i += 1024) {
        unsigned c = hc[i];
        hb[i] = c ? atomicAdd(&gcur[i], c) : 0u;
    }
    __syncthreads();
    for (int i = tid; i < NBk; i += 1024) hc[i] = 0u;
    __syncthreads();
    for (int i = tid; i < T0; i += 1024) {
        int e = base0 + i;
        if (e < E0c) {
            int s = src0[e], d = dst0[e];
            int g = node_graph[d];
            float coef = norm_n[s] * norm_n[d] * norm_e[e];
            unsigned bk = g >> 7;
            unsigned r = atomicAdd(&hc[bk], 1u);
            coarse0[hb[bk] + r] = make_int2(s | ((g & 127) << 19), __float_as_int(coef));
        }
    }
    for (int i = tid; i < T1; i += 1024) {
        int e = base1 + i;
        if (e < E1c) {
            int d = dst1[e];
            unsigned bk = NB0 + (d >> 7);
            unsigned r = atomicAdd(&hc[bk], 1u);
            coarse1[hb[bk] + r - (unsigned)E0c] = src1[e] | ((d & 127) << 17);
        }
    }
}

// ---------------- bucket0: LDS counting sort -> per-wave register gather-reduce ----------------
// 512 threads / 8 waves, NB0=782 blocks (same total waves as old 1563x4)
__global__ __launch_bounds__(512) void k_bucket0(
        const float* __restrict__ x, const int2* __restrict__ coarse0,
        const unsigned* __restrict__ offs, const unsigned* __restrict__ cntN,
        float* __restrict__ r_mean) {
    __shared__ unsigned cur_s[GB0];
    __shared__ unsigned off_s[GB0 + 1];
    __shared__ unsigned short eidx[CAP];
    int B = blockIdx.x, tid = threadIdx.x;
    int g0 = B * GB0;
    int ng = min(GB0, Rc - g0);
    unsigned beg = offs[B], end = offs[B + 1];     // offs[NB0] == E0c
    int n = (int)(end - beg);
    if (n > CAP) n = CAP;
    if (tid < GB0) cur_s[tid] = 0u;
    __syncthreads();
    // counts
    for (int i = tid; i < n; i += 512) {
        int gl = (coarse0[beg + i].x >> 19) & 127;
        atomicAdd(&cur_s[gl], 1u);
    }
    __syncthreads();
    // serial 128-bin exclusive scan
    if (tid == 0) {
        unsigned a = 0;
        for (int i = 0; i < GB0; i++) { unsigned c = cur_s[i]; off_s[i] = a; a += c; }
        off_s[GB0] = a;
    }
    __syncthreads();
    if (tid < GB0) cur_s[tid] = off_s[tid];
    __syncthreads();
    // place local indices
    for (int i = tid; i < n; i += 512) {
        int gl = (coarse0[beg + i].x >> 19) & 127;
        unsigned slot = atomicAdd(&cur_s[gl], 1u);
        eidx[slot] = (unsigned short)i;
    }
    __syncthreads();
    // per-wave gather: wave handles graphs wav, wav+8, ...
    int wav = tid >> 6, lane = tid & 63, q = lane >> 4, l = lane & 15;
    for (int g = wav; g < ng; g += 8) {
        int rbeg = (int)off_s[g], rend = (int)off_s[g + 1];
        float4 acc = {0.f, 0.f, 0.f, 0.f};
        for (int base = rbeg; base < rend; base += 64) {
            int m = min(64, rend - base);
            int s = 0;
            float c = 0.f;
            if (lane < m) {
                int2 p = coarse0[beg + eidx[base + lane]];
                s = p.x & 0x7FFFF;
                c = __int_as_float(p.y);
            }
            int rounds = (m + 3) >> 2;
            for (int t = 0; t < rounds; t++) {
                int idx = 4 * t + q;             // idx >= m broadcasts (0,0) -> adds 0
                int sj = __shfl(s, idx);
                float cj = __shfl(c, idx);
                float4 v = ((const float4*)(x + (size_t)sj * 64))[l];
                acc.x += v.x * cj; acc.y += v.y * cj;
                acc.z += v.z * cj; acc.w += v.w * cj;
            }
        }
        acc.x += __shfl_xor(acc.x, 16); acc.y += __shfl_xor(acc.y, 16);
        acc.z += __shfl_xor(acc.z, 16); acc.w += __shfl_xor(acc.w, 16);
        acc.x += __shfl_xor(acc.x, 32); acc.y += __shfl_xor(acc.y, 32);
        acc.z += __shfl_xor(acc.z, 32); acc.w += __shfl_xor(acc.w, 32);
        if (q == 0) {
            float inv = 1.f / (float)cntN[g0 + g];
            float4 o = {acc.x * inv, acc.y * inv, acc.z * inv, acc.w * inv};
            ((float4*)(r_mean + (size_t)(g0 + g) * 64))[l] = o;
        }
    }
}

// ---------------- register-blocked MLP (unchanged) ----------------
__global__ __launch_bounds__(512) void k_mlp(const float* __restrict__ r_in,
                                             const float* __restrict__ W1,
                                             const float* __restrict__ b1,
                                             const float* __restrict__ Wsrc,
                                             const float* __restrict__ bsrc,
                                             const float* __restrict__ attn,
                                             float* __restrict__ feat,
                                             float* __restrict__ score_src, int R) {
    __shared__ float W1s[64 * 64];
    __shared__ float Wss[64 * 128];
    __shared__ float b1s[64], bss[128], atts[128];
    __shared__ float in_s[MTILE * 68];
    __shared__ float t1_s[MTILE * 68];
    int tid = threadIdx.x;
    for (int i = tid; i < 4096; i += 512) W1s[i] = W1[i];
    for (int i = tid; i < 8192; i += 512) Wss[i] = Wsrc[i];
    if (tid < 64) b1s[tid] = b1[tid];
    if (tid >= 64 && tid < 192) bss[tid - 64] = bsrc[tid - 64];
    if (tid >= 192 && tid < 320) atts[tid - 192] = attn[tid - 192];

    int row = tid >> 4, c = tid & 15;
    size_t grow = (size_t)blockIdx.x * MTILE + row;
    float4 vin = ((const float4*)(r_in + grow * 64))[c];
    *((float4*)&in_s[row * 68 + c * 4]) = vin;
    __syncthreads();

    {
        float4 a = {0.f, 0.f, 0.f, 0.f};
        const float* wcol = W1s + c * 4;
        const float* inr = in_s + row * 68;
#pragma unroll
        for (int k = 0; k < 64; k++) {
            float iv = inr[k];
            float4 w = *((const float4*)(wcol + k * 64));
            a.x += iv * w.x; a.y += iv * w.y;
            a.z += iv * w.z; a.w += iv * w.w;
        }
        const float4 bb = *((const float4*)(b1s + c * 4));
        a.x += bb.x; a.y += bb.y; a.z += bb.z; a.w += bb.w;
        a.x = a.x >= 0.f ? a.x : 0.01f * a.x;
        a.y = a.y >= 0.f ? a.y : 0.01f * a.y;
        a.z = a.z >= 0.f ? a.z : 0.01f * a.z;
        a.w = a.w >= 0.f ? a.w : 0.01f * a.w;
        *((float4*)&t1_s[row * 68 + c * 4]) = a;
    }
    __syncthreads();

    {
        float4 a0 = {0.f, 0.f, 0.f, 0.f}, a1 = {0.f, 0.f, 0.f, 0.f};
        const float* w2 = Wss + c * 8;
        const float* t1r = t1_s + row * 68;
#pragma unroll
        for (int k = 0; k < 64; k++) {
            float tv = t1r[k];
            float4 w0 = *((const float4*)(w2 + k * 128));
            float4 w1 = *((const float4*)(w2 + k * 128 + 4));
            a0.x += tv * w0.x; a0.y += tv * w0.y;
            a0.z += tv * w0.z; a0.w += tv * w0.w;
            a1.x += tv * w1.x; a1.y += tv * w1.y;
            a1.z += tv * w1.z; a1.w += tv * w1.w;
        }
        const float4 b0 = *((const float4*)(bss + c * 8));
        const float4 b1v = *((const float4*)(bss + c * 8 + 4));
        a0.x += b0.x; a0.y += b0.y; a0.z += b0.z; a0.w += b0.w;
        a1.x += b1v.x; a1.y += b1v.y; a1.z += b1v.z; a1.w += b1v.w;
        float4* fp = (float4*)(feat + grow * 128 + c * 8);
        fp[0] = a0; fp[1] = a1;
        const float4 at0 = *((const float4*)(atts + c * 8));
        const float4 at1 = *((const float4*)(atts + c * 8 + 4));
        float p =
            (a0.x >= 0.f ? a0.x : 0.2f * a0.x) * at0.x +
            (a0.y >= 0.f ? a0.y : 0.2f * a0.y) * at0.y +
            (a0.z >= 0.f ? a0.z : 0.2f * a0.z) * at0.z +
            (a0.w >= 0.f ? a0.w : 0.2f * a0.w) * at0.w +
            (a1.x >= 0.f ? a1.x : 0.2f * a1.x) * at1.x +
            (a1.y >= 0.f ? a1.y : 0.2f * a1.y) * at1.y +
            (a1.z >= 0.f ? a1.z : 0.2f * a1.z) * at1.z +
            (a1.w >= 0.f ? a1.w : 0.2f * a1.w) * at1.w;
        p += __shfl_xor(p, 1);
        p += __shfl_xor(p, 2);
        if ((c & 3) == 0) score_src[grow * 4 + (c >> 2)] = p;
    }
}

// ---------------- bucket1: LDS counting sort -> per-wave softmax gather ----------------
// 512 threads / 8 waves, NB1=391 blocks (same total waves as old 782x4)
__global__ __launch_bounds__(512) void k_bucket1(
        const float* __restrict__ feat, const float* __restrict__ score,
        const int* __restrict__ coarse1, const unsigned* __restrict__ offs,
        float* __restrict__ out) {
    __shared__ unsigned cur_s[DB1];
    __shared__ unsigned off_s[DB1 + 1];
    __shared__ unsigned short eidx[CAP];
    int B = blockIdx.x, tid = threadIdx.x;
    int d0 = B * DB1;
    int nd = min(DB1, NDc - d0);
    unsigned beg = offs[NB0 + B] - (unsigned)E0c;
    unsigned end = (B == NB1 - 1) ? (unsigned)E1c : (offs[NB0 + B + 1] - (unsigned)E0c);
    int n = (int)(end - beg);
    if (n > CAP) n = CAP;
    if (tid < DB1) cur_s[tid] = 0u;
    __syncthreads();
    for (int i = tid; i < n; i += 512) {
        int dl = (coarse1[beg + i] >> 17) & 127;
        atomicAdd(&cur_s[dl], 1u);
    }
    __syncthreads();
    if (tid == 0) {
        unsigned a = 0;
        for (int i = 0; i < DB1; i++) { unsigned c = cur_s[i]; off_s[i] = a; a += c; }
        off_s[DB1] = a;
    }
    __syncthreads();
    if (tid < DB1) cur_s[tid] = off_s[tid];
    __syncthreads();
    for (int i = tid; i < n; i += 512) {
        int dl = (coarse1[beg + i] >> 17) & 127;
        unsigned slot = atomicAdd(&cur_s[dl], 1u);
        eidx[slot] = (unsigned short)i;
    }
    __syncthreads();
    int wav = tid >> 6, lane = tid & 63, q = lane >> 5, l = lane & 31, h = l >> 3;
    const float NEG = -3.0e38f;
    for (int dl = wav; dl < nd; dl += 8) {
        int rbeg = (int)off_s[dl], rend = (int)off_s[dl + 1];
        bool single = (rend - rbeg) <= 64;
        float4 mx = {NEG, NEG, NEG, NEG};
        int s_reg = 0;
        float4 sc_reg = {NEG, NEG, NEG, NEG};
        // pass A: per-head max
        for (int base = rbeg; base < rend; base += 64) {
            int m = min(64, rend - base);
            int s = 0;
            float4 sc = {NEG, NEG, NEG, NEG};
            if (lane < m) {
                s = coarse1[beg + eidx[base + lane]] & 0x1FFFF;
                sc = ((const float4*)score)[s];
            }
            if (single) { s_reg = s; sc_reg = sc; }
            mx.x = fmaxf(mx.x, sc.x); mx.y = fmaxf(mx.y, sc.y);
            mx.z = fmaxf(mx.z, sc.z); mx.w = fmaxf(mx.w, sc.w);
        }
#pragma unroll
        for (int o = 1; o < 64; o <<= 1) {
            mx.x = fmaxf(mx.x, __shfl_xor(mx.x, o));
            mx.y = fmaxf(mx.y, __shfl_xor(mx.y, o));
            mx.z = fmaxf(mx.z, __shfl_xor(mx.z, o));
            mx.w = fmaxf(mx.w, __shfl_xor(mx.w, o));
        }
        float mh = h == 0 ? mx.x : h == 1 ? mx.y : h == 2 ? mx.z : mx.w;
        float4 acc = {0.f, 0.f, 0.f, 0.f};
        float sex = 0.f;
        // pass B: acc += exp(score-max) * feat, 2 edges in flight
        for (int base = rbeg; base < rend; base += 64) {
            int m = min(64, rend - base);
            int s;
            float4 sc;
            if (single) {
                s = s_reg; sc = sc_reg;
            } else {
                s = 0; sc.x = sc.y = sc.z = sc.w = NEG;
                if (lane < m) {
                    s = coarse1[beg + eidx[base + lane]] & 0x1FFFF;
                    sc = ((const float4*)score)[s];
                }
            }
            int rounds = (m + 1) >> 1;
            for (int t = 0; t < rounds; t++) {
                int idx = 2 * t + q;
                int sj = __shfl(s, idx);
                float sx = __shfl(sc.x, idx), sy = __shfl(sc.y, idx);
                float sz = __shfl(sc.z, idx), sw = __shfl(sc.w, idx);
                float sch = h == 0 ? sx : h == 1 ? sy : h == 2 ? sz : sw;
                float ex = __expf(sch - mh);
                float4 v = ((const float4*)(feat + (size_t)sj * 128))[l];
                acc.x += v.x * ex; acc.y += v.y * ex;
                acc.z += v.z * ex; acc.w += v.w * ex;
                sex += ex;
            }
        }
        acc.x += __shfl_xor(acc.x, 32); acc.y += __shfl_xor(acc.y, 32);
        acc.z += __shfl_xor(acc.z, 32); acc.w += __shfl_xor(acc.w, 32);
        sex += __shfl_xor(sex, 32);
        float inv = 1.f / sex;
        acc.x *= inv; acc.y *= inv; acc.z *= inv; acc.w *= inv;
        acc.x += __shfl_xor(acc.x, 8);  acc.y += __shfl_xor(acc.y, 8);
        acc.z += __shfl_xor(acc.z, 8);  acc.w += __shfl_xor(acc.w, 8);
        acc.x += __shfl_xor(acc.x, 16); acc.y += __shfl_xor(acc.y, 16);
        acc.z += __shfl_xor(acc.z, 16); acc.w += __shfl_xor(acc.w, 16);
        if (lane < 8) ((float4*)(out + (size_t)(d0 + dl) * 32))[lane] = acc;
    }
}

extern "C" void kernel_launch(void* const* d_in, const int* in_sizes, int n_in,
                              void* d_out, int out_size, void* d_ws, size_t ws_size,
                              hipStream_t stream) {
    const float* x      = (const float*)d_in[0];
    const float* norm_n = (const float*)d_in[1];
    const float* norm_e = (const float*)d_in[2];
    const float* W1     = (const float*)d_in[3];
    const float* b1     = (const float*)d_in[4];
    const float* Wsrc   = (const float*)d_in[5];
    const float* bsrc   = (const float*)d_in[6];
    const float* attn   = (const float*)d_in[7];
    const int* src0     = (const int*)d_in[8];
    const int* dst0     = (const int*)d_in[9];
    const int* node_graph = (const int*)d_in[10];
    const int* src1     = (const int*)d_in[11];
    const int* dst1     = (const int*)d_in[12];
    float* out = (float*)d_out;

    char* ws = (char*)d_ws;
    size_t off = 0;
    auto alloc = [&](size_t bytes) {
        void* p = ws + off;
        off += (bytes + 255) & ~(size_t)255;   // keep 16B+ alignment for float4
        return p;
    };

    unsigned* cnt  = (unsigned*)alloc(NBk * 4);         // zeroed
    unsigned* cntN = (unsigned*)alloc((size_t)Rc * 4);  // zeroed
    size_t zero_bytes = off;
    unsigned* offs = (unsigned*)alloc(NBk * 4);
    unsigned* gcur = (unsigned*)alloc(NBk * 4);
    unsigned* bsum = (unsigned*)alloc(1024 * 4);
    // region A: coarse0 (16 MB) then feat (51.2 MB) — coarse0 dead before k_mlp writes feat
    char* pA = (char*)alloc((size_t)Rc * 128 * 4);
    int2* coarse0 = (int2*)pA;
    float* feat   = (float*)pA;
    int* coarse1  = (int*)alloc((size_t)E1c * 4);
    float* r_mean = (float*)alloc((size_t)Rc * 64 * 4);
    float* score_src = (float*)alloc((size_t)Rc * 4 * 4);

    hipMemsetAsync(d_ws, 0, zero_bytes, stream);

    k_hist_coarse<<<PB, 1024, 0, stream>>>(dst0, node_graph, dst1, cnt, cntN);
    int nb = (NBk + 1023) / 1024;   // 2
    k_scan1<<<nb, 1024, 0, stream>>>(cnt, offs, bsum, NBk);
    k_scan2<<<1, 1024, 0, stream>>>(bsum, nb);
    k_scan3<<<nb, 1024, 0, stream>>>(offs, bsum, gcur, NBk);

    k_place_coarse<<<PB, 1024, 0, stream>>>(src0, dst0, node_graph, norm_n, norm_e,
                                            src1, dst1, gcur, coarse0, coarse1);

    k_bucket0<<<NB0, 512, 0, stream>>>(x, coarse0, offs, cntN, r_mean);
    k_mlp<<<Rc / MTILE, 512, 0, stream>>>(r_mean, W1, b1, Wsrc, bsrc, attn, feat, score_src, Rc);
    k_bucket1<<<NB1, 512, 0, stream>>>(feat, score_src, coarse1, offs, out);
}

// Round 2
// 575.310 us; speedup vs baseline: 1.1398x; 1.0867x over previous
//
#include <hip/hip_runtime.h>
#include <math.h>

#define N0c 500000
#define Rc  100000
#define NDc 50000
#define E0c 2000000
#define E1c 1000000
#define GB0 128                 // graphs per set0 bucket
#define NB0 782                 // ceil(Rc/128)
#define DB1 128                 // dst nodes per set1 bucket
#define NB1 391                 // ceil(NDc/128)
#define NBk (NB0 + NB1)         // 1173
#define T0  8192                // set0 edges per partition tile
#define T1  4096                // set1 edges per partition tile
#define TN  2048                // nodes per partition tile
#define PB  245                 // ceil(E0c/T0); covers E1c/T1 and N0c/TN too
#define CAP 3584                // slab capacity per bucket (mean ~2558, sd ~50 -> 20 sigma)
#define MTILE 32

// ---------------- fused place: tile-local LDS counting sort -> slab reserve -> COALESCED write ----
// Replaces k_hist_coarse + 3 scan kernels + old k_place_coarse.
// coarse0 slab layout: bucket b at [b*CAP, b*CAP+cnt_b) int2; coarse1: bucket b at [b*CAP, ...) int.
// Write pass walks slots in sorted order so consecutive lanes hit consecutive addresses per run.
__global__ __launch_bounds__(1024) void k_place(
        const int* __restrict__ src0, const int* __restrict__ dst0,
        const int* __restrict__ node_graph, const float* __restrict__ norm_n,
        const float* __restrict__ norm_e, const int* __restrict__ src1,
        const int* __restrict__ dst1, unsigned* __restrict__ gcur,
        unsigned* __restrict__ cntN,
        int2* __restrict__ coarse0, int* __restrict__ coarse1) {
    __shared__ unsigned cnt_s[NBk];          // counts, later rank cursors
    __shared__ unsigned lo_s[NBk + 1];       // tile-local exclusive scan
    __shared__ unsigned dst_s[NBk];          // slab_base + reserved - lo  (direct dest = dst_s[b]+j)
    __shared__ unsigned pack_s[T0 + T1];     // slot-ordered packed edges (also scan scratch)

    int tid = threadIdx.x, b = blockIdx.x;
    int base0 = b * T0, base1 = b * T1, baseN = b * TN;

    for (int i = tid; i < NBk; i += 1024) cnt_s[i] = 0u;
    __syncthreads();

    // ---- pass 1: tile histogram (+ global node counts) ----
    for (int i = tid; i < T0; i += 1024) {
        int e = base0 + i;
        if (e < E0c) atomicAdd(&cnt_s[node_graph[dst0[e]] >> 7], 1u);
    }
    for (int i = tid; i < T1; i += 1024) {
        int e = base1 + i;
        if (e < E1c) atomicAdd(&cnt_s[NB0 + (dst1[e] >> 7)], 1u);
    }
    for (int i = tid; i < TN; i += 1024) {
        int n = baseN + i;
        if (n < N0c) atomicAdd(&cntN[node_graph[n]], 1u);
    }
    __syncthreads();

    // ---- pass 2: exclusive scan over NBk bins (2 blocked bins/thread, Hillis-Steele 1024) ----
    unsigned a0 = (2 * tid < NBk) ? cnt_s[2 * tid] : 0u;
    unsigned a1 = (2 * tid + 1 < NBk) ? cnt_s[2 * tid + 1] : 0u;
    unsigned ssum = a0 + a1;
    unsigned* scratch = pack_s;              // pack_s free until rank pass
    scratch[tid] = ssum;
    __syncthreads();
    for (int off = 1; off < 1024; off <<= 1) {
        unsigned t = (tid >= off) ? scratch[tid - off] : 0u;
        __syncthreads();
        scratch[tid] += t;
        __syncthreads();
    }
    unsigned ex = scratch[tid] - ssum;
    if (2 * tid < NBk) lo_s[2 * tid] = ex;
    if (2 * tid + 1 < NBk) lo_s[2 * tid + 1] = ex + a0;
    if (tid == 1023) lo_s[NBk] = scratch[1023];
    __syncthreads();

    // ---- pass 3: reserve slab ranges; fold slab base and -lo into dst_s ----
    {
        int b0i = 2 * tid, b1i = 2 * tid + 1;
        if (b0i < NBk) {
            unsigned c = cnt_s[b0i];
            unsigned rb = c ? atomicAdd(&gcur[b0i], c) : 0u;
            unsigned sb = (b0i < NB0) ? (unsigned)b0i * CAP : (unsigned)(b0i - NB0) * CAP;
            dst_s[b0i] = sb + rb - lo_s[b0i];
        }
        if (b1i < NBk) {
            unsigned c = cnt_s[b1i];
            unsigned rb = c ? atomicAdd(&gcur[b1i], c) : 0u;
            unsigned sb = (b1i < NB0) ? (unsigned)b1i * CAP : (unsigned)(b1i - NB0) * CAP;
            dst_s[b1i] = sb + rb - lo_s[b1i];
        }
    }
    __syncthreads();
    for (int i = tid; i < NBk; i += 1024) cnt_s[i] = lo_s[i];   // rank cursors
    __syncthreads();

    // ---- pass 4: rank edges into slot order ----
    // set0 pack: i(13b) | glow(7b)<<13 | bk(10b)<<20     set1 pack: i(12b) | dlow(7b)<<12 | bk1(9b)<<19
    for (int i = tid; i < T0; i += 1024) {
        int e = base0 + i;
        if (e < E0c) {
            int g = node_graph[dst0[e]];
            unsigned bk = (unsigned)g >> 7;
            unsigned slot = atomicAdd(&cnt_s[bk], 1u);
            pack_s[slot] = (unsigned)i | ((unsigned)(g & 127) << 13) | (bk << 20);
        }
    }
    for (int i = tid; i < T1; i += 1024) {
        int e = base1 + i;
        if (e < E1c) {
            int d = dst1[e];
            unsigned bk1 = (unsigned)d >> 7;
            unsigned slot = atomicAdd(&cnt_s[NB0 + bk1], 1u);
            pack_s[slot] = (unsigned)i | ((unsigned)(d & 127) << 12) | (bk1 << 19);
        }
    }
    __syncthreads();

    // ---- pass 5: coalesced slab write (consecutive j in a run -> consecutive addresses) ----
    unsigned n0 = lo_s[NB0];
    unsigned ntot = lo_s[NBk];
    for (unsigned j = tid; j < ntot; j += 1024) {
        unsigned pk = pack_s[j];
        if (j < n0) {
            unsigned i = pk & 8191u;
            unsigned glow = (pk >> 13) & 127u;
            unsigned bk = pk >> 20;
            unsigned idx = dst_s[bk] + j;
            if (idx - bk * CAP < CAP) {          // slab overflow guard (20 sigma, ~never)
                int e = base0 + (int)i;
                int s = src0[e], d = dst0[e];
                float coef = norm_n[s] * norm_n[d] * norm_e[e];
                coarse0[idx] = make_int2(s | (int)(glow << 19), __float_as_int(coef));
            }
        } else {
            unsigned i = pk & 4095u;
            unsigned dlow = (pk >> 12) & 127u;
            unsigned bk1 = pk >> 19;
            unsigned idx = dst_s[NB0 + bk1] + j;
            if (idx - bk1 * CAP < CAP) {
                int e = base1 + (int)i;
                coarse1[idx] = src1[e] | (int)(dlow << 17);
            }
        }
    }
}

// ---------------- bucket0: LDS counting sort -> per-wave register gather-reduce ----------------
__global__ __launch_bounds__(512) void k_bucket0(
        const float* __restrict__ x, const int2* __restrict__ coarse0,
        const unsigned* __restrict__ gcur, const unsigned* __restrict__ cntN,
        float* __restrict__ r_mean) {
    __shared__ unsigned cur_s[GB0];
    __shared__ unsigned off_s[GB0 + 1];
    __shared__ unsigned short eidx[CAP];
    int B = blockIdx.x, tid = threadIdx.x;
    int g0 = B * GB0;
    int ng = min(GB0, Rc - g0);
    size_t beg = (size_t)B * CAP;                 // slab base
    int n = min((int)gcur[B], CAP);
    if (tid < GB0) cur_s[tid] = 0u;
    __syncthreads();
    // counts
    for (int i = tid; i < n; i += 512) {
        int gl = (coarse0[beg + i].x >> 19) & 127;
        atomicAdd(&cur_s[gl], 1u);
    }
    __syncthreads();
    // serial 128-bin exclusive scan
    if (tid == 0) {
        unsigned a = 0;
        for (int i = 0; i < GB0; i++) { unsigned c = cur_s[i]; off_s[i] = a; a += c; }
        off_s[GB0] = a;
    }
    __syncthreads();
    if (tid < GB0) cur_s[tid] = off_s[tid];
    __syncthreads();
    // place local indices
    for (int i = tid; i < n; i += 512) {
        int gl = (coarse0[beg + i].x >> 19) & 127;
        unsigned slot = atomicAdd(&cur_s[gl], 1u);
        eidx[slot] = (unsigned short)i;
    }
    __syncthreads();
    // per-wave gather: wave handles graphs wav, wav+8, ...
    int wav = tid >> 6, lane = tid & 63, q = lane >> 4, l = lane & 15;
    for (int g = wav; g < ng; g += 8) {
        int rbeg = (int)off_s[g], rend = (int)off_s[g + 1];
        float4 acc = {0.f, 0.f, 0.f, 0.f};
        for (int base = rbeg; base < rend; base += 64) {
            int m = min(64, rend - base);
            int s = 0;
            float c = 0.f;
            if (lane < m) {
                int2 p = coarse0[beg + eidx[base + lane]];
                s = p.x & 0x7FFFF;
                c = __int_as_float(p.y);
            }
            int rounds = (m + 3) >> 2;
            for (int t = 0; t < rounds; t++) {
                int idx = 4 * t + q;             // idx >= m broadcasts (0,0) -> adds 0
                int sj = __shfl(s, idx);
                float cj = __shfl(c, idx);
                float4 v = ((const float4*)(x + (size_t)sj * 64))[l];
                acc.x += v.x * cj; acc.y += v.y * cj;
                acc.z += v.z * cj; acc.w += v.w * cj;
            }
        }
        acc.x += __shfl_xor(acc.x, 16); acc.y += __shfl_xor(acc.y, 16);
        acc.z += __shfl_xor(acc.z, 16); acc.w += __shfl_xor(acc.w, 16);
        acc.x += __shfl_xor(acc.x, 32); acc.y += __shfl_xor(acc.y, 32);
        acc.z += __shfl_xor(acc.z, 32); acc.w += __shfl_xor(acc.w, 32);
        if (q == 0) {
            float inv = 1.f / (float)cntN[g0 + g];
            float4 o = {acc.x * inv, acc.y * inv, acc.z * inv, acc.w * inv};
            ((float4*)(r_mean + (size_t)(g0 + g) * 64))[l] = o;
        }
    }
}

// ---------------- register-blocked MLP (unchanged) ----------------
__global__ __launch_bounds__(512) void k_mlp(const float* __restrict__ r_in,
                                             const float* __restrict__ W1,
                                             const float* __restrict__ b1,
                                             const float* __restrict__ Wsrc,
                                             const float* __restrict__ bsrc,
                                             const float* __restrict__ attn,
                                             float* __restrict__ feat,
                                             float* __restrict__ score_src, int R) {
    __shared__ float W1s[64 * 64];
    __shared__ float Wss[64 * 128];
    __shared__ float b1s[64], bss[128], atts[128];
    __shared__ float in_s[MTILE * 68];
    __shared__ float t1_s[MTILE * 68];
    int tid = threadIdx.x;
    for (int i = tid; i < 4096; i += 512) W1s[i] = W1[i];
    for (int i = tid; i < 8192; i += 512) Wss[i] = Wsrc[i];
    if (tid < 64) b1s[tid] = b1[tid];
    if (tid >= 64 && tid < 192) bss[tid - 64] = bsrc[tid - 64];
    if (tid >= 192 && tid < 320) atts[tid - 192] = attn[tid - 192];

    int row = tid >> 4, c = tid & 15;
    size_t grow = (size_t)blockIdx.x * MTILE + row;
    float4 vin = ((const float4*)(r_in + grow * 64))[c];
    *((float4*)&in_s[row * 68 + c * 4]) = vin;
    __syncthreads();

    {
        float4 a = {0.f, 0.f, 0.f, 0.f};
        const float* wcol = W1s + c * 4;
        const float* inr = in_s + row * 68;
#pragma unroll
        for (int k = 0; k < 64; k++) {
            float iv = inr[k];
            float4 w = *((const float4*)(wcol + k * 64));
            a.x += iv * w.x; a.y += iv * w.y;
            a.z += iv * w.z; a.w += iv * w.w;
        }
        const float4 bb = *((const float4*)(b1s + c * 4));
        a.x += bb.x; a.y += bb.y; a.z += bb.z; a.w += bb.w;
        a.x = a.x >= 0.f ? a.x : 0.01f * a.x;
        a.y = a.y >= 0.f ? a.y : 0.01f * a.y;
        a.z = a.z >= 0.f ? a.z : 0.01f * a.z;
        a.w = a.w >= 0.f ? a.w : 0.01f * a.w;
        *((float4*)&t1_s[row * 68 + c * 4]) = a;
    }
    __syncthreads();

    {
        float4 a0 = {0.f, 0.f, 0.f, 0.f}, a1 = {0.f, 0.f, 0.f, 0.f};
        const float* w2 = Wss + c * 8;
        const float* t1r = t1_s + row * 68;
#pragma unroll
        for (int k = 0; k < 64; k++) {
            float tv = t1r[k];
            float4 w0 = *((const float4*)(w2 + k * 128));
            float4 w1 = *((const float4*)(w2 + k * 128 + 4));
            a0.x += tv * w0.x; a0.y += tv * w0.y;
            a0.z += tv * w0.z; a0.w += tv * w0.w;
            a1.x += tv * w1.x; a1.y += tv * w1.y;
            a1.z += tv * w1.z; a1.w += tv * w1.w;
        }
        const float4 b0 = *((const float4*)(bss + c * 8));
        const float4 b1v = *((const float4*)(bss + c * 8 + 4));
        a0.x += b0.x; a0.y += b0.y; a0.z += b0.z; a0.w += b0.w;
        a1.x += b1v.x; a1.y += b1v.y; a1.z += b1v.z; a1.w += b1v.w;
        float4* fp = (float4*)(feat + grow * 128 + c * 8);
        fp[0] = a0; fp[1] = a1;
        const float4 at0 = *((const float4*)(atts + c * 8));
        const float4 at1 = *((const float4*)(atts + c * 8 + 4));
        float p =
            (a0.x >= 0.f ? a0.x : 0.2f * a0.x) * at0.x +
            (a0.y >= 0.f ? a0.y : 0.2f * a0.y) * at0.y +
            (a0.z >= 0.f ? a0.z : 0.2f * a0.z) * at0.z +
            (a0.w >= 0.f ? a0.w : 0.2f * a0.w) * at0.w +
            (a1.x >= 0.f ? a1.x : 0.2f * a1.x) * at1.x +
            (a1.y >= 0.f ? a1.y : 0.2f * a1.y) * at1.y +
            (a1.z >= 0.f ? a1.z : 0.2f * a1.z) * at1.z +
            (a1.w >= 0.f ? a1.w : 0.2f * a1.w) * at1.w;
        p += __shfl_xor(p, 1);
        p += __shfl_xor(p, 2);
        if ((c & 3) == 0) score_src[grow * 4 + (c >> 2)] = p;
    }
}

// ---------------- bucket1: LDS counting sort -> per-wave softmax gather ----------------
__global__ __launch_bounds__(512) void k_bucket1(
        const float* __restrict__ feat, const float* __restrict__ score,
        const int* __restrict__ coarse1, const unsigned* __restrict__ gcur,
        float* __restrict__ out) {
    __shared__ unsigned cur_s[DB1];
    __shared__ unsigned off_s[DB1 + 1];
    __shared__ unsigned short eidx[CAP];
    int B = blockIdx.x, tid = threadIdx.x;
    int d0 = B * DB1;
    int nd = min(DB1, NDc - d0);
    size_t beg = (size_t)B * CAP;                 // slab base into coarse1
    int n = min((int)gcur[NB0 + B], CAP);
    if (tid < DB1) cur_s[tid] = 0u;
    __syncthreads();
    for (int i = tid; i < n; i += 512) {
        int dl = (coarse1[beg + i] >> 17) & 127;
        atomicAdd(&cur_s[dl], 1u);
    }
    __syncthreads();
    if (tid == 0) {
        unsigned a = 0;
        for (int i = 0; i < DB1; i++) { unsigned c = cur_s[i]; off_s[i] = a; a += c; }
        off_s[DB1] = a;
    }
    __syncthreads();
    if (tid < DB1) cur_s[tid] = off_s[tid];
    __syncthreads();
    for (int i = tid; i < n; i += 512) {
        int dl = (coarse1[beg + i] >> 17) & 127;
        unsigned slot = atomicAdd(&cur_s[dl], 1u);
        eidx[slot] = (unsigned short)i;
    }
    __syncthreads();
    int wav = tid >> 6, lane = tid & 63, q = lane >> 5, l = lane & 31, h = l >> 3;
    const float NEG = -3.0e38f;
    for (int dl = wav; dl < nd; dl += 8) {
        int rbeg = (int)off_s[dl], rend = (int)off_s[dl + 1];
        bool single = (rend - rbeg) <= 64;
        float4 mx = {NEG, NEG, NEG, NEG};
        int s_reg = 0;
        float4 sc_reg = {NEG, NEG, NEG, NEG};
        // pass A: per-head max
        for (int base = rbeg; base < rend; base += 64) {
            int m = min(64, rend - base);
            int s = 0;
            float4 sc = {NEG, NEG, NEG, NEG};
            if (lane < m) {
                s = coarse1[beg + eidx[base + lane]] & 0x1FFFF;
                sc = ((const float4*)score)[s];
            }
            if (single) { s_reg = s; sc_reg = sc; }
            mx.x = fmaxf(mx.x, sc.x); mx.y = fmaxf(mx.y, sc.y);
            mx.z = fmaxf(mx.z, sc.z); mx.w = fmaxf(mx.w, sc.w);
        }
#pragma unroll
        for (int o = 1; o < 64; o <<= 1) {
            mx.x = fmaxf(mx.x, __shfl_xor(mx.x, o));
            mx.y = fmaxf(mx.y, __shfl_xor(mx.y, o));
            mx.z = fmaxf(mx.z, __shfl_xor(mx.z, o));
            mx.w = fmaxf(mx.w, __shfl_xor(mx.w, o));
        }
        float mh = h == 0 ? mx.x : h == 1 ? mx.y : h == 2 ? mx.z : mx.w;
        float4 acc = {0.f, 0.f, 0.f, 0.f};
        float sex = 0.f;
        // pass B: acc += exp(score-max) * feat, 2 edges in flight
        for (int base = rbeg; base < rend; base += 64) {
            int m = min(64, rend - base);
            int s;
            float4 sc;
            if (single) {
                s = s_reg; sc = sc_reg;
            } else {
                s = 0; sc.x = sc.y = sc.z = sc.w = NEG;
                if (lane < m) {
                    s = coarse1[beg + eidx[base + lane]] & 0x1FFFF;
                    sc = ((const float4*)score)[s];
                }
            }
            int rounds = (m + 1) >> 1;
            for (int t = 0; t < rounds; t++) {
                int idx = 2 * t + q;
                int sj = __shfl(s, idx);
                float sx = __shfl(sc.x, idx), sy = __shfl(sc.y, idx);
                float sz = __shfl(sc.z, idx), sw = __shfl(sc.w, idx);
                float sch = h == 0 ? sx : h == 1 ? sy : h == 2 ? sz : sw;
                float ex = __expf(sch - mh);
                float4 v = ((const float4*)(feat + (size_t)sj * 128))[l];
                acc.x += v.x * ex; acc.y += v.y * ex;
                acc.z += v.z * ex; acc.w += v.w * ex;
                sex += ex;
            }
        }
        acc.x += __shfl_xor(acc.x, 32); acc.y += __shfl_xor(acc.y, 32);
        acc.z += __shfl_xor(acc.z, 32); acc.w += __shfl_xor(acc.w, 32);
        sex += __shfl_xor(sex, 32);
        float inv = 1.f / sex;
        acc.x *= inv; acc.y *= inv; acc.z *= inv; acc.w *= inv;
        acc.x += __shfl_xor(acc.x, 8);  acc.y += __shfl_xor(acc.y, 8);
        acc.z += __shfl_xor(acc.z, 8);  acc.w += __shfl_xor(acc.w, 8);
        acc.x += __shfl_xor(acc.x, 16); acc.y += __shfl_xor(acc.y, 16);
        acc.z += __shfl_xor(acc.z, 16); acc.w += __shfl_xor(acc.w, 16);
        if (lane < 8) ((float4*)(out + (size_t)(d0 + dl) * 32))[lane] = acc;
    }
}

extern "C" void kernel_launch(void* const* d_in, const int* in_sizes, int n_in,
                              void* d_out, int out_size, void* d_ws, size_t ws_size,
                              hipStream_t stream) {
    const float* x      = (const float*)d_in[0];
    const float* norm_n = (const float*)d_in[1];
    const float* norm_e = (const float*)d_in[2];
    const float* W1     = (const float*)d_in[3];
    const float* b1     = (const float*)d_in[4];
    const float* Wsrc   = (const float*)d_in[5];
    const float* bsrc   = (const float*)d_in[6];
    const float* attn   = (const float*)d_in[7];
    const int* src0     = (const int*)d_in[8];
    const int* dst0     = (const int*)d_in[9];
    const int* node_graph = (const int*)d_in[10];
    const int* src1     = (const int*)d_in[11];
    const int* dst1     = (const int*)d_in[12];
    float* out = (float*)d_out;

    char* ws = (char*)d_ws;
    size_t off = 0;
    auto alloc = [&](size_t bytes) {
        void* p = ws + off;
        off += (bytes + 255) & ~(size_t)255;   // keep 16B+ alignment for float4
        return p;
    };

    unsigned* gcur = (unsigned*)alloc(NBk * 4);         // zeroed (slab bump cursors / counts)
    unsigned* cntN = (unsigned*)alloc((size_t)Rc * 4);  // zeroed
    size_t zero_bytes = off;
    // region A: coarse0 slab (NB0*CAP*8 = 22.4 MB) then feat (51.2 MB) — coarse0 dead before k_mlp
    size_t featB = (size_t)Rc * 128 * 4;
    char* pA = (char*)alloc(featB);
    int2* coarse0 = (int2*)pA;
    float* feat   = (float*)pA;
    int* coarse1  = (int*)alloc((size_t)NB1 * CAP * 4); // 5.6 MB slab
    float* r_mean = (float*)alloc((size_t)Rc * 64 * 4);
    float* score_src = (float*)alloc((size_t)Rc * 4 * 4);

    hipMemsetAsync(d_ws, 0, zero_bytes, stream);

    k_place<<<PB, 1024, 0, stream>>>(src0, dst0, node_graph, norm_n, norm_e,
                                     src1, dst1, gcur, cntN, coarse0, coarse1);

    k_bucket0<<<NB0, 512, 0, stream>>>(x, coarse0, gcur, cntN, r_mean);
    k_mlp<<<Rc / MTILE, 512, 0, stream>>>(r_mean, W1, b1, Wsrc, bsrc, attn, feat, score_src, Rc);
    k_bucket1<<<NB1, 512, 0, stream>>>(feat, score_src, coarse1, gcur, out);
}

// Round 3
// 541.114 us; speedup vs baseline: 1.2119x; 1.0632x over previous
//
#include <hip/hip_runtime.h>
#include <math.h>

#define N0c 500000
#define Rc  100000
#define NDc 50000
#define E0c 2000000
#define E1c 1000000
#define GB0 128                 // graphs per set0 bucket
#define NB0 782                 // ceil(Rc/128)
#define DB1 128                 // dst nodes per set1 bucket
#define NB1 391                 // ceil(NDc/128)
#define NBk (NB0 + NB1)         // 1173
#define T0  8192                // set0 edges per partition tile
#define T1  4096                // set1 edges per partition tile
#define TN  2048                // nodes per partition tile
#define PB  245                 // ceil(E0c/T0); covers E1c/T1 and N0c/TN too
#define CAP 3584                // slab capacity per bucket (mean ~2558, sd ~50 -> 20 sigma)
#define MTILE 32

// ---------------- fused place: tile-local LDS counting sort -> slab reserve -> COALESCED write ----
__global__ __launch_bounds__(1024) void k_place(
        const int* __restrict__ src0, const int* __restrict__ dst0,
        const int* __restrict__ node_graph, const float* __restrict__ norm_n,
        const float* __restrict__ norm_e, const int* __restrict__ src1,
        const int* __restrict__ dst1, unsigned* __restrict__ gcur,
        unsigned* __restrict__ cntN,
        int2* __restrict__ coarse0, int* __restrict__ coarse1) {
    __shared__ unsigned cnt_s[NBk];          // counts, later rank cursors
    __shared__ unsigned lo_s[NBk + 1];       // tile-local exclusive scan
    __shared__ unsigned dst_s[NBk];          // slab_base + reserved - lo  (direct dest = dst_s[b]+j)
    __shared__ unsigned pack_s[T0 + T1];     // slot-ordered packed edges (also scan scratch)

    int tid = threadIdx.x, b = blockIdx.x;
    int base0 = b * T0, base1 = b * T1, baseN = b * TN;

    for (int i = tid; i < NBk; i += 1024) cnt_s[i] = 0u;
    __syncthreads();

    // ---- pass 1: tile histogram (+ global node counts) ----
    for (int i = tid; i < T0; i += 1024) {
        int e = base0 + i;
        if (e < E0c) atomicAdd(&cnt_s[node_graph[dst0[e]] >> 7], 1u);
    }
    for (int i = tid; i < T1; i += 1024) {
        int e = base1 + i;
        if (e < E1c) atomicAdd(&cnt_s[NB0 + (dst1[e] >> 7)], 1u);
    }
    for (int i = tid; i < TN; i += 1024) {
        int n = baseN + i;
        if (n < N0c) atomicAdd(&cntN[node_graph[n]], 1u);
    }
    __syncthreads();

    // ---- pass 2: exclusive scan over NBk bins (2 blocked bins/thread, Hillis-Steele 1024) ----
    unsigned a0 = (2 * tid < NBk) ? cnt_s[2 * tid] : 0u;
    unsigned a1 = (2 * tid + 1 < NBk) ? cnt_s[2 * tid + 1] : 0u;
    unsigned ssum = a0 + a1;
    unsigned* scratch = pack_s;              // pack_s free until rank pass
    scratch[tid] = ssum;
    __syncthreads();
    for (int off = 1; off < 1024; off <<= 1) {
        unsigned t = (tid >= off) ? scratch[tid - off] : 0u;
        __syncthreads();
        scratch[tid] += t;
        __syncthreads();
    }
    unsigned ex = scratch[tid] - ssum;
    if (2 * tid < NBk) lo_s[2 * tid] = ex;
    if (2 * tid + 1 < NBk) lo_s[2 * tid + 1] = ex + a0;
    if (tid == 1023) lo_s[NBk] = scratch[1023];
    __syncthreads();

    // ---- pass 3: reserve slab ranges; fold slab base and -lo into dst_s ----
    {
        int b0i = 2 * tid, b1i = 2 * tid + 1;
        if (b0i < NBk) {
            unsigned c = cnt_s[b0i];
            unsigned rb = c ? atomicAdd(&gcur[b0i], c) : 0u;
            unsigned sb = (b0i < NB0) ? (unsigned)b0i * CAP : (unsigned)(b0i - NB0) * CAP;
            dst_s[b0i] = sb + rb - lo_s[b0i];
        }
        if (b1i < NBk) {
            unsigned c = cnt_s[b1i];
            unsigned rb = c ? atomicAdd(&gcur[b1i], c) : 0u;
            unsigned sb = (b1i < NB0) ? (unsigned)b1i * CAP : (unsigned)(b1i - NB0) * CAP;
            dst_s[b1i] = sb + rb - lo_s[b1i];
        }
    }
    __syncthreads();
    for (int i = tid; i < NBk; i += 1024) cnt_s[i] = lo_s[i];   // rank cursors
    __syncthreads();

    // ---- pass 4: rank edges into slot order ----
    // set0 pack: i(13b) | glow(7b)<<13 | bk(10b)<<20     set1 pack: i(12b) | dlow(7b)<<12 | bk1(9b)<<19
    for (int i = tid; i < T0; i += 1024) {
        int e = base0 + i;
        if (e < E0c) {
            int g = node_graph[dst0[e]];
            unsigned bk = (unsigned)g >> 7;
            unsigned slot = atomicAdd(&cnt_s[bk], 1u);
            pack_s[slot] = (unsigned)i | ((unsigned)(g & 127) << 13) | (bk << 20);
        }
    }
    for (int i = tid; i < T1; i += 1024) {
        int e = base1 + i;
        if (e < E1c) {
            int d = dst1[e];
            unsigned bk1 = (unsigned)d >> 7;
            unsigned slot = atomicAdd(&cnt_s[NB0 + bk1], 1u);
            pack_s[slot] = (unsigned)i | ((unsigned)(d & 127) << 12) | (bk1 << 19);
        }
    }
    __syncthreads();

    // ---- pass 5: coalesced slab write (consecutive j in a run -> consecutive addresses) ----
    unsigned n0 = lo_s[NB0];
    unsigned ntot = lo_s[NBk];
    for (unsigned j = tid; j < ntot; j += 1024) {
        unsigned pk = pack_s[j];
        if (j < n0) {
            unsigned i = pk & 8191u;
            unsigned glow = (pk >> 13) & 127u;
            unsigned bk = pk >> 20;
            unsigned idx = dst_s[bk] + j;
            if (idx - bk * CAP < CAP) {          // slab overflow guard (20 sigma, ~never)
                int e = base0 + (int)i;
                int s = src0[e], d = dst0[e];
                float coef = norm_n[s] * norm_n[d] * norm_e[e];
                coarse0[idx] = make_int2(s | (int)(glow << 19), __float_as_int(coef));
            }
        } else {
            unsigned i = pk & 4095u;
            unsigned dlow = (pk >> 12) & 127u;
            unsigned bk1 = pk >> 19;
            unsigned idx = dst_s[NB0 + bk1] + j;
            if (idx - bk1 * CAP < CAP) {
                int e = base1 + (int)i;
                coarse1[idx] = src1[e] | (int)(dlow << 17);
            }
        }
    }
}

// ---------------- bucket0: LDS counting sort (payload in LDS) -> 4-deep pipelined gather ----------
__global__ __launch_bounds__(512) void k_bucket0(
        const float* __restrict__ x, const int2* __restrict__ coarse0,
        const unsigned* __restrict__ gcur, const unsigned* __restrict__ cntN,
        float* __restrict__ r_mean) {
    __shared__ unsigned cur_s[GB0];
    __shared__ unsigned off_s[GB0 + 1];
    __shared__ int   sa[CAP];
    __shared__ float ca[CAP];
    int B = blockIdx.x, tid = threadIdx.x;
    int g0 = B * GB0;
    int ng = min(GB0, Rc - g0);
    size_t beg = (size_t)B * CAP;                 // slab base
    int n = min((int)gcur[B], CAP);
    if (tid < GB0) cur_s[tid] = 0u;
    __syncthreads();
    // counts
    for (int i = tid; i < n; i += 512) {
        int gl = (coarse0[beg + i].x >> 19) & 127;
        atomicAdd(&cur_s[gl], 1u);
    }
    __syncthreads();
    // wave-0 shuffle scan over 128 bins (2/lane)
    if (tid < 64) {
        unsigned b0 = cur_s[2 * tid], b1 = cur_s[2 * tid + 1];
        unsigned ssum = b0 + b1;
        unsigned sc = ssum;
        for (int o = 1; o < 64; o <<= 1) {
            unsigned t = __shfl_up(sc, o);
            if (tid >= o) sc += t;
        }
        unsigned ex = sc - ssum;
        off_s[2 * tid] = ex;
        off_s[2 * tid + 1] = ex + b0;
        if (tid == 63) off_s[GB0] = sc;
    }
    __syncthreads();
    if (tid < GB0) cur_s[tid] = off_s[tid];
    __syncthreads();
    // place payload (src, coef) into LDS in sorted slot order
    for (int i = tid; i < n; i += 512) {
        int2 p = coarse0[beg + i];
        int gl = (p.x >> 19) & 127;
        unsigned slot = atomicAdd(&cur_s[gl], 1u);
        sa[slot] = p.x & 0x7FFFF;
        ca[slot] = __int_as_float(p.y);
    }
    __syncthreads();
    // per-wave gather: 4 quarter-wave groups, 4 rows in flight each trip
    int wav = tid >> 6, lane = tid & 63, q = lane >> 4, l = lane & 15;
    for (int g = wav; g < ng; g += 8) {
        int rbeg = (int)off_s[g], rend = (int)off_s[g + 1];
        float4 acc = {0.f, 0.f, 0.f, 0.f};
        for (int j0 = rbeg + q; j0 < rend; j0 += 16) {
            int j1 = j0 + 4, j2 = j0 + 8, j3 = j0 + 12;
            int s0 = sa[j0];                 float c0 = ca[j0];
            int s1 = 0; float c1 = 0.f;
            int s2 = 0; float c2 = 0.f;
            int s3 = 0; float c3 = 0.f;
            if (j1 < rend) { s1 = sa[j1]; c1 = ca[j1]; }
            if (j2 < rend) { s2 = sa[j2]; c2 = ca[j2]; }
            if (j3 < rend) { s3 = sa[j3]; c3 = ca[j3]; }
            float4 v0 = ((const float4*)(x + (size_t)s0 * 64))[l];
            float4 v1 = ((const float4*)(x + (size_t)s1 * 64))[l];
            float4 v2 = ((const float4*)(x + (size_t)s2 * 64))[l];
            float4 v3 = ((const float4*)(x + (size_t)s3 * 64))[l];
            acc.x += v0.x * c0 + v1.x * c1 + v2.x * c2 + v3.x * c3;
            acc.y += v0.y * c0 + v1.y * c1 + v2.y * c2 + v3.y * c3;
            acc.z += v0.z * c0 + v1.z * c1 + v2.z * c2 + v3.z * c3;
            acc.w += v0.w * c0 + v1.w * c1 + v2.w * c2 + v3.w * c3;
        }
        acc.x += __shfl_xor(acc.x, 16); acc.y += __shfl_xor(acc.y, 16);
        acc.z += __shfl_xor(acc.z, 16); acc.w += __shfl_xor(acc.w, 16);
        acc.x += __shfl_xor(acc.x, 32); acc.y += __shfl_xor(acc.y, 32);
        acc.z += __shfl_xor(acc.z, 32); acc.w += __shfl_xor(acc.w, 32);
        if (q == 0) {
            float inv = 1.f / (float)cntN[g0 + g];
            float4 o = {acc.x * inv, acc.y * inv, acc.z * inv, acc.w * inv};
            ((float4*)(r_mean + (size_t)(g0 + g) * 64))[l] = o;
        }
    }
}

// ---------------- register-blocked MLP (unchanged) ----------------
__global__ __launch_bounds__(512) void k_mlp(const float* __restrict__ r_in,
                                             const float* __restrict__ W1,
                                             const float* __restrict__ b1,
                                             const float* __restrict__ Wsrc,
                                             const float* __restrict__ bsrc,
                                             const float* __restrict__ attn,
                                             float* __restrict__ feat,
                                             float* __restrict__ score_src, int R) {
    __shared__ float W1s[64 * 64];
    __shared__ float Wss[64 * 128];
    __shared__ float b1s[64], bss[128], atts[128];
    __shared__ float in_s[MTILE * 68];
    __shared__ float t1_s[MTILE * 68];
    int tid = threadIdx.x;
    for (int i = tid; i < 4096; i += 512) W1s[i] = W1[i];
    for (int i = tid; i < 8192; i += 512) Wss[i] = Wsrc[i];
    if (tid < 64) b1s[tid] = b1[tid];
    if (tid >= 64 && tid < 192) bss[tid - 64] = bsrc[tid - 64];
    if (tid >= 192 && tid < 320) atts[tid - 192] = attn[tid - 192];

    int row = tid >> 4, c = tid & 15;
    size_t grow = (size_t)blockIdx.x * MTILE + row;
    float4 vin = ((const float4*)(r_in + grow * 64))[c];
    *((float4*)&in_s[row * 68 + c * 4]) = vin;
    __syncthreads();

    {
        float4 a = {0.f, 0.f, 0.f, 0.f};
        const float* wcol = W1s + c * 4;
        const float* inr = in_s + row * 68;
#pragma unroll
        for (int k = 0; k < 64; k++) {
            float iv = inr[k];
            float4 w = *((const float4*)(wcol + k * 64));
            a.x += iv * w.x; a.y += iv * w.y;
            a.z += iv * w.z; a.w += iv * w.w;
        }
        const float4 bb = *((const float4*)(b1s + c * 4));
        a.x += bb.x; a.y += bb.y; a.z += bb.z; a.w += bb.w;
        a.x = a.x >= 0.f ? a.x : 0.01f * a.x;
        a.y = a.y >= 0.f ? a.y : 0.01f * a.y;
        a.z = a.z >= 0.f ? a.z : 0.01f * a.z;
        a.w = a.w >= 0.f ? a.w : 0.01f * a.w;
        *((float4*)&t1_s[row * 68 + c * 4]) = a;
    }
    __syncthreads();

    {
        float4 a0 = {0.f, 0.f, 0.f, 0.f}, a1 = {0.f, 0.f, 0.f, 0.f};
        const float* w2 = Wss + c * 8;
        const float* t1r = t1_s + row * 68;
#pragma unroll
        for (int k = 0; k < 64; k++) {
            float tv = t1r[k];
            float4 w0 = *((const float4*)(w2 + k * 128));
            float4 w1 = *((const float4*)(w2 + k * 128 + 4));
            a0.x += tv * w0.x; a0.y += tv * w0.y;
            a0.z += tv * w0.z; a0.w += tv * w0.w;
            a1.x += tv * w1.x; a1.y += tv * w1.y;
            a1.z += tv * w1.z; a1.w += tv * w1.w;
        }
        const float4 b0 = *((const float4*)(bss + c * 8));
        const float4 b1v = *((const float4*)(bss + c * 8 + 4));
        a0.x += b0.x; a0.y += b0.y; a0.z += b0.z; a0.w += b0.w;
        a1.x += b1v.x; a1.y += b1v.y; a1.z += b1v.z; a1.w += b1v.w;
        float4* fp = (float4*)(feat + grow * 128 + c * 8);
        fp[0] = a0; fp[1] = a1;
        const float4 at0 = *((const float4*)(atts + c * 8));
        const float4 at1 = *((const float4*)(atts + c * 8 + 4));
        float p =
            (a0.x >= 0.f ? a0.x : 0.2f * a0.x) * at0.x +
            (a0.y >= 0.f ? a0.y : 0.2f * a0.y) * at0.y +
            (a0.z >= 0.f ? a0.z : 0.2f * a0.z) * at0.z +
            (a0.w >= 0.f ? a0.w : 0.2f * a0.w) * at0.w +
            (a1.x >= 0.f ? a1.x : 0.2f * a1.x) * at1.x +
            (a1.y >= 0.f ? a1.y : 0.2f * a1.y) * at1.y +
            (a1.z >= 0.f ? a1.z : 0.2f * a1.z) * at1.z +
            (a1.w >= 0.f ? a1.w : 0.2f * a1.w) * at1.w;
        p += __shfl_xor(p, 1);
        p += __shfl_xor(p, 2);
        if ((c & 3) == 0) score_src[grow * 4 + (c >> 2)] = p;
    }
}

// ---------------- bucket1: LDS counting sort (src in LDS) -> 4-deep pipelined softmax gather -----
__global__ __launch_bounds__(512) void k_bucket1(
        const float* __restrict__ feat, const float* __restrict__ score,
        const int* __restrict__ coarse1, const unsigned* __restrict__ gcur,
        float* __restrict__ out) {
    __shared__ unsigned cur_s[DB1];
    __shared__ unsigned off_s[DB1 + 1];
    __shared__ int sa[CAP];
    int B = blockIdx.x, tid = threadIdx.x;
    int d0 = B * DB1;
    int nd = min(DB1, NDc - d0);
    size_t beg = (size_t)B * CAP;                 // slab base into coarse1
    int n = min((int)gcur[NB0 + B], CAP);
    if (tid < DB1) cur_s[tid] = 0u;
    __syncthreads();
    for (int i = tid; i < n; i += 512) {
        int dl = (coarse1[beg + i] >> 17) & 127;
        atomicAdd(&cur_s[dl], 1u);
    }
    __syncthreads();
    if (tid < 64) {
        unsigned b0 = cur_s[2 * tid], b1 = cur_s[2 * tid + 1];
        unsigned ssum = b0 + b1;
        unsigned sc = ssum;
        for (int o = 1; o < 64; o <<= 1) {
            unsigned t = __shfl_up(sc, o);
            if (tid >= o) sc += t;
        }
        unsigned ex = sc - ssum;
        off_s[2 * tid] = ex;
        off_s[2 * tid + 1] = ex + b0;
        if (tid == 63) off_s[DB1] = sc;
    }
    __syncthreads();
    if (tid < DB1) cur_s[tid] = off_s[tid];
    __syncthreads();
    for (int i = tid; i < n; i += 512) {
        int p = coarse1[beg + i];
        int dl = (p >> 17) & 127;
        unsigned slot = atomicAdd(&cur_s[dl], 1u);
        sa[slot] = p & 0x1FFFF;
    }
    __syncthreads();
    int wav = tid >> 6, lane = tid & 63, q = lane >> 5, l = lane & 31, h = l >> 3;
    const float NEG = -3.0e38f;
    for (int dl = wav; dl < nd; dl += 8) {
        int rbeg = (int)off_s[dl], rend = (int)off_s[dl + 1];
        // pass A: per-head max (lane strides edges)
        float4 mx = {NEG, NEG, NEG, NEG};
        for (int j = rbeg + lane; j < rend; j += 64) {
            int s = sa[j];
            float4 sc = ((const float4*)score)[s];
            mx.x = fmaxf(mx.x, sc.x); mx.y = fmaxf(mx.y, sc.y);
            mx.z = fmaxf(mx.z, sc.z); mx.w = fmaxf(mx.w, sc.w);
        }
#pragma unroll
        for (int o = 1; o < 64; o <<= 1) {
            mx.x = fmaxf(mx.x, __shfl_xor(mx.x, o));
            mx.y = fmaxf(mx.y, __shfl_xor(mx.y, o));
            mx.z = fmaxf(mx.z, __shfl_xor(mx.z, o));
            mx.w = fmaxf(mx.w, __shfl_xor(mx.w, o));
        }
        float mh = h == 0 ? mx.x : h == 1 ? mx.y : h == 2 ? mx.z : mx.w;
        float4 acc = {0.f, 0.f, 0.f, 0.f};
        float sex = 0.f;
        // pass B: two half-wave groups, 4 edges in flight each trip
        for (int j0 = rbeg + q; j0 < rend; j0 += 8) {
            int j1 = j0 + 2, j2 = j0 + 4, j3 = j0 + 6;
            int s0 = sa[j0];
            bool v1 = j1 < rend, v2 = j2 < rend, v3 = j3 < rend;
            int s1 = v1 ? sa[j1] : s0;
            int s2 = v2 ? sa[j2] : s0;
            int s3 = v3 ? sa[j3] : s0;
            float sc0 = score[4 * s0 + h];
            float sc1 = score[4 * s1 + h];
            float sc2 = score[4 * s2 + h];
            float sc3 = score[4 * s3 + h];
            float4 f0 = ((const float4*)(feat + (size_t)s0 * 128))[l];
            float4 f1 = ((const float4*)(feat + (size_t)s1 * 128))[l];
            float4 f2 = ((const float4*)(feat + (size_t)s2 * 128))[l];
            float4 f3 = ((const float4*)(feat + (size_t)s3 * 128))[l];
            float e0 = __expf(sc0 - mh);
            float e1 = v1 ? __expf(sc1 - mh) : 0.f;
            float e2 = v2 ? __expf(sc2 - mh) : 0.f;
            float e3 = v3 ? __expf(sc3 - mh) : 0.f;
            acc.x += f0.x * e0 + f1.x * e1 + f2.x * e2 + f3.x * e3;
            acc.y += f0.y * e0 + f1.y * e1 + f2.y * e2 + f3.y * e3;
            acc.z += f0.z * e0 + f1.z * e1 + f2.z * e2 + f3.z * e3;
            acc.w += f0.w * e0 + f1.w * e1 + f2.w * e2 + f3.w * e3;
            sex += e0 + e1 + e2 + e3;
        }
        acc.x += __shfl_xor(acc.x, 32); acc.y += __shfl_xor(acc.y, 32);
        acc.z += __shfl_xor(acc.z, 32); acc.w += __shfl_xor(acc.w, 32);
        sex += __shfl_xor(sex, 32);
        float inv = 1.f / sex;
        acc.x *= inv; acc.y *= inv; acc.z *= inv; acc.w *= inv;
        acc.x += __shfl_xor(acc.x, 8);  acc.y += __shfl_xor(acc.y, 8);
        acc.z += __shfl_xor(acc.z, 8);  acc.w += __shfl_xor(acc.w, 8);
        acc.x += __shfl_xor(acc.x, 16); acc.y += __shfl_xor(acc.y, 16);
        acc.z += __shfl_xor(acc.z, 16); acc.w += __shfl_xor(acc.w, 16);
        if (lane < 8) ((float4*)(out + (size_t)(d0 + dl) * 32))[lane] = acc;
    }
}

extern "C" void kernel_launch(void* const* d_in, const int* in_sizes, int n_in,
                              void* d_out, int out_size, void* d_ws, size_t ws_size,
                              hipStream_t stream) {
    const float* x      = (const float*)d_in[0];
    const float* norm_n = (const float*)d_in[1];
    const float* norm_e = (const float*)d_in[2];
    const float* W1     = (const float*)d_in[3];
    const float* b1     = (const float*)d_in[4];
    const float* Wsrc   = (const float*)d_in[5];
    const float* bsrc   = (const float*)d_in[6];
    const float* attn   = (const float*)d_in[7];
    const int* src0     = (const int*)d_in[8];
    const int* dst0     = (const int*)d_in[9];
    const int* node_graph = (const int*)d_in[10];
    const int* src1     = (const int*)d_in[11];
    const int* dst1     = (const int*)d_in[12];
    float* out = (float*)d_out;

    char* ws = (char*)d_ws;
    size_t off = 0;
    auto alloc = [&](size_t bytes) {
        void* p = ws + off;
        off += (bytes + 255) & ~(size_t)255;   // keep 16B+ alignment for float4
        return p;
    };

    unsigned* gcur = (unsigned*)alloc(NBk * 4);         // zeroed (slab bump cursors / counts)
    unsigned* cntN = (unsigned*)alloc((size_t)Rc * 4);  // zeroed
    size_t zero_bytes = off;
    // region A: coarse0 slab (NB0*CAP*8 = 22.4 MB) then feat (51.2 MB) — coarse0 dead before k_mlp
    size_t featB = (size_t)Rc * 128 * 4;
    char* pA = (char*)alloc(featB);
    int2* coarse0 = (int2*)pA;
    float* feat   = (float*)pA;
    int* coarse1  = (int*)alloc((size_t)NB1 * CAP * 4); // 5.6 MB slab
    float* r_mean = (float*)alloc((size_t)Rc * 64 * 4);
    float* score_src = (float*)alloc((size_t)Rc * 4 * 4);

    hipMemsetAsync(d_ws, 0, zero_bytes, stream);

    k_place<<<PB, 1024, 0, stream>>>(src0, dst0, node_graph, norm_n, norm_e,
                                     src1, dst1, gcur, cntN, coarse0, coarse1);

    k_bucket0<<<NB0, 512, 0, stream>>>(x, coarse0, gcur, cntN, r_mean);
    k_mlp<<<Rc / MTILE, 512, 0, stream>>>(r_mean, W1, b1, Wsrc, bsrc, attn, feat, score_src, Rc);
    k_bucket1<<<NB1, 512, 0, stream>>>(feat, score_src, coarse1, gcur, out);
}

// Round 4
// 510.910 us; speedup vs baseline: 1.2835x; 1.0591x over previous
//
#include <hip/hip_runtime.h>
#include <math.h>

#define N0c 500000
#define Rc  100000
#define NDc 50000
#define E0c 2000000
#define E1c 1000000
#define GB0 128                 // graphs per set0 bucket
#define NB0 782                 // ceil(Rc/128)
#define DB1 128                 // dst nodes per set1 bucket
#define NB1 391                 // ceil(NDc/128)
#define NBk (NB0 + NB1)         // 1173
#define T0  4096                // set0 edges per partition tile
#define T1  2048                // set1 edges per partition tile
#define TN  1024                // nodes per partition tile
#define PB  489                 // ceil(E0c/T0) == ceil(E1c/T1) == ceil(N0c/TN)
#define CAP 3584                // slab capacity per bucket (mean ~2558, sd ~50 -> 20 sigma)
#define MTILE 32

// ---------------- fused place v2: gather-once into LDS -> rank from LDS -> coalesced slab write --
// LDS 77.7 KB -> 2 blocks/CU (32 waves, was 16). pack word: i(12b) | low(7b)<<12 | bkAll(11b)<<19
__global__ __launch_bounds__(1024) void k_place(
        const int* __restrict__ src0, const int* __restrict__ dst0,
        const int* __restrict__ node_graph, const float* __restrict__ norm_n,
        const float* __restrict__ norm_e, const int* __restrict__ src1,
        const int* __restrict__ dst1, unsigned* __restrict__ gcur,
        unsigned* __restrict__ cntN,
        int2* __restrict__ coarse0, int* __restrict__ coarse1) {
    __shared__ unsigned cnt_s[NBk];          // counts, later rank cursors
    __shared__ unsigned lo_s[NBk + 1];       // tile-local exclusive scan
    __shared__ unsigned dst_s[NBk];          // slab_base + reserved - lo  (direct dest = dst_s[b]+j)
    __shared__ unsigned pack_e[T0 + T1];     // per-edge pack, built in pass 1 (gather-once)
    __shared__ unsigned pack_s[T0 + T1];     // slot-ordered packs (also scan scratch)
    __shared__ float    pc_s[T0];            // partial coef norm_n[d]*norm_e[e] for set0

    int tid = threadIdx.x, b = blockIdx.x;
    int base0 = b * T0, base1 = b * T1, baseN = b * TN;

    for (int i = tid; i < NBk; i += 1024) cnt_s[i] = 0u;
    __syncthreads();

    // ---- pass 1: gather chain ONCE; hist + pack + partial coef (+ global node counts) ----
    for (int i = tid; i < T0; i += 1024) {
        int e = base0 + i;
        if (e < E0c) {
            int d = dst0[e];
            int g = node_graph[d];
            unsigned bk = (unsigned)g >> 7;
            atomicAdd(&cnt_s[bk], 1u);
            pack_e[i] = (unsigned)i | ((unsigned)(g & 127) << 12) | (bk << 19);
            pc_s[i] = norm_n[d] * norm_e[e];
        }
    }
    for (int i = tid; i < T1; i += 1024) {
        int e = base1 + i;
        if (e < E1c) {
            int d = dst1[e];
            unsigned bkAll = NB0 + ((unsigned)d >> 7);
            atomicAdd(&cnt_s[bkAll], 1u);
            pack_e[T0 + i] = (unsigned)i | ((unsigned)(d & 127) << 12) | (bkAll << 19);
        }
    }
    for (int i = tid; i < TN; i += 1024) {
        int n = baseN + i;
        if (n < N0c) atomicAdd(&cntN[node_graph[n]], 1u);
    }
    __syncthreads();

    // ---- pass 2: exclusive scan over NBk bins (2 blocked bins/thread, Hillis-Steele 1024) ----
    unsigned a0 = (2 * tid < NBk) ? cnt_s[2 * tid] : 0u;
    unsigned a1 = (2 * tid + 1 < NBk) ? cnt_s[2 * tid + 1] : 0u;
    unsigned ssum = a0 + a1;
    unsigned* scratch = pack_s;              // pack_s free until rank pass
    scratch[tid] = ssum;
    __syncthreads();
    for (int off = 1; off < 1024; off <<= 1) {
        unsigned t = (tid >= off) ? scratch[tid - off] : 0u;
        __syncthreads();
        scratch[tid] += t;
        __syncthreads();
    }
    unsigned ex = scratch[tid] - ssum;
    if (2 * tid < NBk) lo_s[2 * tid] = ex;
    if (2 * tid + 1 < NBk) lo_s[2 * tid + 1] = ex + a0;
    if (tid == 1023) lo_s[NBk] = scratch[1023];
    __syncthreads();

    // ---- pass 3: reserve slab ranges; fold slab base and -lo into dst_s ----
    {
        int b0i = 2 * tid, b1i = 2 * tid + 1;
        if (b0i < NBk) {
            unsigned c = cnt_s[b0i];
            unsigned rb = c ? atomicAdd(&gcur[b0i], c) : 0u;
            unsigned sb = (b0i < NB0) ? (unsigned)b0i * CAP : (unsigned)(b0i - NB0) * CAP;
            dst_s[b0i] = sb + rb - lo_s[b0i];
        }
        if (b1i < NBk) {
            unsigned c = cnt_s[b1i];
            unsigned rb = c ? atomicAdd(&gcur[b1i], c) : 0u;
            unsigned sb = (b1i < NB0) ? (unsigned)b1i * CAP : (unsigned)(b1i - NB0) * CAP;
            dst_s[b1i] = sb + rb - lo_s[b1i];
        }
    }
    __syncthreads();
    for (int i = tid; i < NBk; i += 1024) cnt_s[i] = lo_s[i];   // rank cursors
    __syncthreads();

    // ---- pass 4: rank edges into slot order (LDS-only, no global re-gather) ----
    for (int i = tid; i < T0; i += 1024) {
        if (base0 + i < E0c) {
            unsigned pk = pack_e[i];
            unsigned bk = pk >> 19;
            unsigned slot = atomicAdd(&cnt_s[bk], 1u);
            pack_s[slot] = pk;
        }
    }
    for (int i = tid; i < T1; i += 1024) {
        if (base1 + i < E1c) {
            unsigned pk = pack_e[T0 + i];
            unsigned bk = pk >> 19;
            unsigned slot = atomicAdd(&cnt_s[bk], 1u);
            pack_s[slot] = pk;
        }
    }
    __syncthreads();

    // ---- pass 5: coalesced slab write (consecutive j in a run -> consecutive addresses) ----
    unsigned ntot = lo_s[NBk];
    for (unsigned j = tid; j < ntot; j += 1024) {
        unsigned pk = pack_s[j];
        unsigned bkAll = pk >> 19;
        unsigned low = (pk >> 12) & 127u;
        unsigned i = pk & 4095u;
        unsigned idx = dst_s[bkAll] + j;
        if (bkAll < NB0) {
            if (idx - bkAll * CAP < CAP) {       // slab overflow guard (20 sigma, ~never)
                int e = base0 + (int)i;
                int s = src0[e];
                float coef = pc_s[i] * norm_n[s];
                coarse0[idx] = make_int2(s | (int)(low << 19), __float_as_int(coef));
            }
        } else {
            if (idx - (bkAll - NB0) * CAP < CAP) {
                int e = base1 + (int)i;
                coarse1[idx] = src1[e] | (int)(low << 17);
            }
        }
    }
}

// ---------------- bucket0: LDS counting sort (payload in LDS) -> 4-deep pipelined gather ----------
__global__ __launch_bounds__(512) void k_bucket0(
        const float* __restrict__ x, const int2* __restrict__ coarse0,
        const unsigned* __restrict__ gcur, const unsigned* __restrict__ cntN,
        float* __restrict__ r_mean) {
    __shared__ unsigned cur_s[GB0];
    __shared__ unsigned off_s[GB0 + 1];
    __shared__ int   sa[CAP];
    __shared__ float ca[CAP];
    int B = blockIdx.x, tid = threadIdx.x;
    int g0 = B * GB0;
    int ng = min(GB0, Rc - g0);
    size_t beg = (size_t)B * CAP;                 // slab base
    int n = min((int)gcur[B], CAP);
    if (tid < GB0) cur_s[tid] = 0u;
    __syncthreads();
    // counts
    for (int i = tid; i < n; i += 512) {
        int gl = (coarse0[beg + i].x >> 19) & 127;
        atomicAdd(&cur_s[gl], 1u);
    }
    __syncthreads();
    // wave-0 shuffle scan over 128 bins (2/lane)
    if (tid < 64) {
        unsigned b0 = cur_s[2 * tid], b1 = cur_s[2 * tid + 1];
        unsigned ssum = b0 + b1;
        unsigned sc = ssum;
        for (int o = 1; o < 64; o <<= 1) {
            unsigned t = __shfl_up(sc, o);
            if (tid >= o) sc += t;
        }
        unsigned ex = sc - ssum;
        off_s[2 * tid] = ex;
        off_s[2 * tid + 1] = ex + b0;
        if (tid == 63) off_s[GB0] = sc;
    }
    __syncthreads();
    if (tid < GB0) cur_s[tid] = off_s[tid];
    __syncthreads();
    // place payload (src, coef) into LDS in sorted slot order
    for (int i = tid; i < n; i += 512) {
        int2 p = coarse0[beg + i];
        int gl = (p.x >> 19) & 127;
        unsigned slot = atomicAdd(&cur_s[gl], 1u);
        sa[slot] = p.x & 0x7FFFF;
        ca[slot] = __int_as_float(p.y);
    }
    __syncthreads();
    // per-wave gather: 4 quarter-wave groups, 4 rows in flight each trip
    int wav = tid >> 6, lane = tid & 63, q = lane >> 4, l = lane & 15;
    for (int g = wav; g < ng; g += 8) {
        int rbeg = (int)off_s[g], rend = (int)off_s[g + 1];
        float4 acc = {0.f, 0.f, 0.f, 0.f};
        for (int j0 = rbeg + q; j0 < rend; j0 += 16) {
            int j1 = j0 + 4, j2 = j0 + 8, j3 = j0 + 12;
            int s0 = sa[j0];                 float c0 = ca[j0];
            int s1 = 0; float c1 = 0.f;
            int s2 = 0; float c2 = 0.f;
            int s3 = 0; float c3 = 0.f;
            if (j1 < rend) { s1 = sa[j1]; c1 = ca[j1]; }
            if (j2 < rend) { s2 = sa[j2]; c2 = ca[j2]; }
            if (j3 < rend) { s3 = sa[j3]; c3 = ca[j3]; }
            float4 v0 = ((const float4*)(x + (size_t)s0 * 64))[l];
            float4 v1 = ((const float4*)(x + (size_t)s1 * 64))[l];
            float4 v2 = ((const float4*)(x + (size_t)s2 * 64))[l];
            float4 v3 = ((const float4*)(x + (size_t)s3 * 64))[l];
            acc.x += v0.x * c0 + v1.x * c1 + v2.x * c2 + v3.x * c3;
            acc.y += v0.y * c0 + v1.y * c1 + v2.y * c2 + v3.y * c3;
            acc.z += v0.z * c0 + v1.z * c1 + v2.z * c2 + v3.z * c3;
            acc.w += v0.w * c0 + v1.w * c1 + v2.w * c2 + v3.w * c3;
        }
        acc.x += __shfl_xor(acc.x, 16); acc.y += __shfl_xor(acc.y, 16);
        acc.z += __shfl_xor(acc.z, 16); acc.w += __shfl_xor(acc.w, 16);
        acc.x += __shfl_xor(acc.x, 32); acc.y += __shfl_xor(acc.y, 32);
        acc.z += __shfl_xor(acc.z, 32); acc.w += __shfl_xor(acc.w, 32);
        if (q == 0) {
            float inv = 1.f / (float)cntN[g0 + g];
            float4 o = {acc.x * inv, acc.y * inv, acc.z * inv, acc.w * inv};
            ((float4*)(r_mean + (size_t)(g0 + g) * 64))[l] = o;
        }
    }
}

// ---------------- register-blocked MLP (unchanged) ----------------
__global__ __launch_bounds__(512) void k_mlp(const float* __restrict__ r_in,
                                             const float* __restrict__ W1,
                                             const float* __restrict__ b1,
                                             const float* __restrict__ Wsrc,
                                             const float* __restrict__ bsrc,
                                             const float* __restrict__ attn,
                                             float* __restrict__ feat,
                                             float* __restrict__ score_src, int R) {
    __shared__ float W1s[64 * 64];
    __shared__ float Wss[64 * 128];
    __shared__ float b1s[64], bss[128], atts[128];
    __shared__ float in_s[MTILE * 68];
    __shared__ float t1_s[MTILE * 68];
    int tid = threadIdx.x;
    for (int i = tid; i < 4096; i += 512) W1s[i] = W1[i];
    for (int i = tid; i < 8192; i += 512) Wss[i] = Wsrc[i];
    if (tid < 64) b1s[tid] = b1[tid];
    if (tid >= 64 && tid < 192) bss[tid - 64] = bsrc[tid - 64];
    if (tid >= 192 && tid < 320) atts[tid - 192] = attn[tid - 192];

    int row = tid >> 4, c = tid & 15;
    size_t grow = (size_t)blockIdx.x * MTILE + row;
    float4 vin = ((const float4*)(r_in + grow * 64))[c];
    *((float4*)&in_s[row * 68 + c * 4]) = vin;
    __syncthreads();

    {
        float4 a = {0.f, 0.f, 0.f, 0.f};
        const float* wcol = W1s + c * 4;
        const float* inr = in_s + row * 68;
#pragma unroll
        for (int k = 0; k < 64; k++) {
            float iv = inr[k];
            float4 w = *((const float4*)(wcol + k * 64));
            a.x += iv * w.x; a.y += iv * w.y;
            a.z += iv * w.z; a.w += iv * w.w;
        }
        const float4 bb = *((const float4*)(b1s + c * 4));
        a.x += bb.x; a.y += bb.y; a.z += bb.z; a.w += bb.w;
        a.x = a.x >= 0.f ? a.x : 0.01f * a.x;
        a.y = a.y >= 0.f ? a.y : 0.01f * a.y;
        a.z = a.z >= 0.f ? a.z : 0.01f * a.z;
        a.w = a.w >= 0.f ? a.w : 0.01f * a.w;
        *((float4*)&t1_s[row * 68 + c * 4]) = a;
    }
    __syncthreads();

    {
        float4 a0 = {0.f, 0.f, 0.f, 0.f}, a1 = {0.f, 0.f, 0.f, 0.f};
        const float* w2 = Wss + c * 8;
        const float* t1r = t1_s + row * 68;
#pragma unroll
        for (int k = 0; k < 64; k++) {
            float tv = t1r[k];
            float4 w0 = *((const float4*)(w2 + k * 128));
            float4 w1 = *((const float4*)(w2 + k * 128 + 4));
            a0.x += tv * w0.x; a0.y += tv * w0.y;
            a0.z += tv * w0.z; a0.w += tv * w0.w;
            a1.x += tv * w1.x; a1.y += tv * w1.y;
            a1.z += tv * w1.z; a1.w += tv * w1.w;
        }
        const float4 b0 = *((const float4*)(bss + c * 8));
        const float4 b1v = *((const float4*)(bss + c * 8 + 4));
        a0.x += b0.x; a0.y += b0.y; a0.z += b0.z; a0.w += b0.w;
        a1.x += b1v.x; a1.y += b1v.y; a1.z += b1v.z; a1.w += b1v.w;
        float4* fp = (float4*)(feat + grow * 128 + c * 8);
        fp[0] = a0; fp[1] = a1;
        const float4 at0 = *((const float4*)(atts + c * 8));
        const float4 at1 = *((const float4*)(atts + c * 8 + 4));
        float p =
            (a0.x >= 0.f ? a0.x : 0.2f * a0.x) * at0.x +
            (a0.y >= 0.f ? a0.y : 0.2f * a0.y) * at0.y +
            (a0.z >= 0.f ? a0.z : 0.2f * a0.z) * at0.z +
            (a0.w >= 0.f ? a0.w : 0.2f * a0.w) * at0.w +
            (a1.x >= 0.f ? a1.x : 0.2f * a1.x) * at1.x +
            (a1.y >= 0.f ? a1.y : 0.2f * a1.y) * at1.y +
            (a1.z >= 0.f ? a1.z : 0.2f * a1.z) * at1.z +
            (a1.w >= 0.f ? a1.w : 0.2f * a1.w) * at1.w;
        p += __shfl_xor(p, 1);
        p += __shfl_xor(p, 2);
        if ((c & 3) == 0) score_src[grow * 4 + (c >> 2)] = p;
    }
}

// ---------------- bucket1: LDS counting sort (src in LDS) -> 4-deep pipelined softmax gather -----
__global__ __launch_bounds__(512) void k_bucket1(
        const float* __restrict__ feat, const float* __restrict__ score,
        const int* __restrict__ coarse1, const unsigned* __restrict__ gcur,
        float* __restrict__ out) {
    __shared__ unsigned cur_s[DB1];
    __shared__ unsigned off_s[DB1 + 1];
    __shared__ int sa[CAP];
    int B = blockIdx.x, tid = threadIdx.x;
    int d0 = B * DB1;
    int nd = min(DB1, NDc - d0);
    size_t beg = (size_t)B * CAP;                 // slab base into coarse1
    int n = min((int)gcur[NB0 + B], CAP);
    if (tid < DB1) cur_s[tid] = 0u;
    __syncthreads();
    for (int i = tid; i < n; i += 512) {
        int dl = (coarse1[beg + i] >> 17) & 127;
        atomicAdd(&cur_s[dl], 1u);
    }
    __syncthreads();
    if (tid < 64) {
        unsigned b0 = cur_s[2 * tid], b1 = cur_s[2 * tid + 1];
        unsigned ssum = b0 + b1;
        unsigned sc = ssum;
        for (int o = 1; o < 64; o <<= 1) {
            unsigned t = __shfl_up(sc, o);
            if (tid >= o) sc += t;
        }
        unsigned ex = sc - ssum;
        off_s[2 * tid] = ex;
        off_s[2 * tid + 1] = ex + b0;
        if (tid == 63) off_s[DB1] = sc;
    }
    __syncthreads();
    if (tid < DB1) cur_s[tid] = off_s[tid];
    __syncthreads();
    for (int i = tid; i < n; i += 512) {
        int p = coarse1[beg + i];
        int dl = (p >> 17) & 127;
        unsigned slot = atomicAdd(&cur_s[dl], 1u);
        sa[slot] = p & 0x1FFFF;
    }
    __syncthreads();
    int wav = tid >> 6, lane = tid & 63, q = lane >> 5, l = lane & 31, h = l >> 3;
    const float NEG = -3.0e38f;
    for (int dl = wav; dl < nd; dl += 8) {
        int rbeg = (int)off_s[dl], rend = (int)off_s[dl + 1];
        // pass A: per-head max (lane strides edges)
        float4 mx = {NEG, NEG, NEG, NEG};
        for (int j = rbeg + lane; j < rend; j += 64) {
            int s = sa[j];
            float4 sc = ((const float4*)score)[s];
            mx.x = fmaxf(mx.x, sc.x); mx.y = fmaxf(mx.y, sc.y);
            mx.z = fmaxf(mx.z, sc.z); mx.w = fmaxf(mx.w, sc.w);
        }
#pragma unroll
        for (int o = 1; o < 64; o <<= 1) {
            mx.x = fmaxf(mx.x, __shfl_xor(mx.x, o));
            mx.y = fmaxf(mx.y, __shfl_xor(mx.y, o));
            mx.z = fmaxf(mx.z, __shfl_xor(mx.z, o));
            mx.w = fmaxf(mx.w, __shfl_xor(mx.w, o));
        }
        float mh = h == 0 ? mx.x : h == 1 ? mx.y : h == 2 ? mx.z : mx.w;
        float4 acc = {0.f, 0.f, 0.f, 0.f};
        float sex = 0.f;
        // pass B: two half-wave groups, 4 edges in flight each trip
        for (int j0 = rbeg + q; j0 < rend; j0 += 8) {
            int j1 = j0 + 2, j2 = j0 + 4, j3 = j0 + 6;
            int s0 = sa[j0];
            bool v1 = j1 < rend, v2 = j2 < rend, v3 = j3 < rend;
            int s1 = v1 ? sa[j1] : s0;
            int s2 = v2 ? sa[j2] : s0;
            int s3 = v3 ? sa[j3] : s0;
            float sc0 = score[4 * s0 + h];
            float sc1 = score[4 * s1 + h];
            float sc2 = score[4 * s2 + h];
            float sc3 = score[4 * s3 + h];
            float4 f0 = ((const float4*)(feat + (size_t)s0 * 128))[l];
            float4 f1 = ((const float4*)(feat + (size_t)s1 * 128))[l];
            float4 f2 = ((const float4*)(feat + (size_t)s2 * 128))[l];
            float4 f3 = ((const float4*)(feat + (size_t)s3 * 128))[l];
            float e0 = __expf(sc0 - mh);
            float e1 = v1 ? __expf(sc1 - mh) : 0.f;
            float e2 = v2 ? __expf(sc2 - mh) : 0.f;
            float e3 = v3 ? __expf(sc3 - mh) : 0.f;
            acc.x += f0.x * e0 + f1.x * e1 + f2.x * e2 + f3.x * e3;
            acc.y += f0.y * e0 + f1.y * e1 + f2.y * e2 + f3.y * e3;
            acc.z += f0.z * e0 + f1.z * e1 + f2.z * e2 + f3.z * e3;
            acc.w += f0.w * e0 + f1.w * e1 + f2.w * e2 + f3.w * e3;
            sex += e0 + e1 + e2 + e3;
        }
        acc.x += __shfl_xor(acc.x, 32); acc.y += __shfl_xor(acc.y, 32);
        acc.z += __shfl_xor(acc.z, 32); acc.w += __shfl_xor(acc.w, 32);
        sex += __shfl_xor(sex, 32);
        float inv = 1.f / sex;
        acc.x *= inv; acc.y *= inv; acc.z *= inv; acc.w *= inv;
        acc.x += __shfl_xor(acc.x, 8);  acc.y += __shfl_xor(acc.y, 8);
        acc.z += __shfl_xor(acc.z, 8);  acc.w += __shfl_xor(acc.w, 8);
        acc.x += __shfl_xor(acc.x, 16); acc.y += __shfl_xor(acc.y, 16);
        acc.z += __shfl_xor(acc.z, 16); acc.w += __shfl_xor(acc.w, 16);
        if (lane < 8) ((float4*)(out + (size_t)(d0 + dl) * 32))[lane] = acc;
    }
}

extern "C" void kernel_launch(void* const* d_in, const int* in_sizes, int n_in,
                              void* d_out, int out_size, void* d_ws, size_t ws_size,
                              hipStream_t stream) {
    const float* x      = (const float*)d_in[0];
    const float* norm_n = (const float*)d_in[1];
    const float* norm_e = (const float*)d_in[2];
    const float* W1     = (const float*)d_in[3];
    const float* b1     = (const float*)d_in[4];
    const float* Wsrc   = (const float*)d_in[5];
    const float* bsrc   = (const float*)d_in[6];
    const float* attn   = (const float*)d_in[7];
    const int* src0     = (const int*)d_in[8];
    const int* dst0     = (const int*)d_in[9];
    const int* node_graph = (const int*)d_in[10];
    const int* src1     = (const int*)d_in[11];
    const int* dst1     = (const int*)d_in[12];
    float* out = (float*)d_out;

    char* ws = (char*)d_ws;
    size_t off = 0;
    auto alloc = [&](size_t bytes) {
        void* p = ws + off;
        off += (bytes + 255) & ~(size_t)255;   // keep 16B+ alignment for float4
        return p;
    };

    unsigned* gcur = (unsigned*)alloc(NBk * 4);         // zeroed (slab bump cursors / counts)
    unsigned* cntN = (unsigned*)alloc((size_t)Rc * 4);  // zeroed
    size_t zero_bytes = off;
    // region A: coarse0 slab (NB0*CAP*8 = 22.4 MB) then feat (51.2 MB) — coarse0 dead before k_mlp
    size_t featB = (size_t)Rc * 128 * 4;
    char* pA = (char*)alloc(featB);
    int2* coarse0 = (int2*)pA;
    float* feat   = (float*)pA;
    int* coarse1  = (int*)alloc((size_t)NB1 * CAP * 4); // 5.6 MB slab
    float* r_mean = (float*)alloc((size_t)Rc * 64 * 4);
    float* score_src = (float*)alloc((size_t)Rc * 4 * 4);

    hipMemsetAsync(d_ws, 0, zero_bytes, stream);

    k_place<<<PB, 1024, 0, stream>>>(src0, dst0, node_graph, norm_n, norm_e,
                                     src1, dst1, gcur, cntN, coarse0, coarse1);

    k_bucket0<<<NB0, 512, 0, stream>>>(x, coarse0, gcur, cntN, r_mean);
    k_mlp<<<Rc / MTILE, 512, 0, stream>>>(r_mean, W1, b1, Wsrc, bsrc, attn, feat, score_src, Rc);
    k_bucket1<<<NB1, 512, 0, stream>>>(feat, score_src, coarse1, gcur, out);
}